// Round 2
// baseline (876.976 us; speedup 1.0000x reference)
//
#include <hip/hip_runtime.h>
#include <math.h>

#define Nn 1024
#define Cn 192
#define KEPT 256
#define COMP 512
#define UT 128
#define KT 64
#define C4 48   // Cn/4

// ---------------- Kernel A: w[b][c] = 1 / sum_n x[b][n][c]^2 ----------------
// 768 threads: 4 n-quarters x 192 c. Coalesced scalar loads, LDS combine.
__global__ __launch_bounds__(768) void norm_kernel(const float* __restrict__ x,
                                                   float* __restrict__ w) {
    __shared__ float red[4][Cn];
    int b = blockIdx.x;
    int t = threadIdx.x;
    int nq = t / Cn;          // 0..3
    int c  = t % Cn;
    const float* xb = x + (size_t)b * Nn * Cn + (size_t)nq * 256 * Cn + c;
    float s0 = 0.f, s1 = 0.f, s2 = 0.f, s3 = 0.f;
    for (int n = 0; n < 256; n += 4) {
        float v0 = xb[(n + 0) * Cn];
        float v1 = xb[(n + 1) * Cn];
        float v2 = xb[(n + 2) * Cn];
        float v3 = xb[(n + 3) * Cn];
        s0 += v0 * v0; s1 += v1 * v1; s2 += v2 * v2; s3 += v3 * v3;
    }
    red[nq][c] = (s0 + s1) + (s2 + s3);
    __syncthreads();
    if (t < Cn)
        w[b * Cn + t] = 1.0f / (red[0][t] + red[1][t] + red[2][t] + red[3][t]);
}

// ------------- Kernel B: dst_idx[b][u] = argmax_k sim (k=0 excluded) -------------
// 512 threads. Lane map: tk = t&15 (4 k each), ch = (t>>4)&1 (c4-half), ti = t>>5 (8 u each).
// Tile 128u x 64k per kt pass; C split across ch, combined via shfl_xor(16).
// su linear (a-reads are 16-lane broadcasts); sk row-swizzled (c4 ^ ((r>>2)&7)).
__global__ __launch_bounds__(512, 2) void sim_argmax_kernel(const float* __restrict__ x,
                                                            const float* __restrict__ w,
                                                            int* __restrict__ dst_idx) {
    __shared__ float4 su[UT * C4];    // 98304 B
    __shared__ float4 sk[KT * C4];    // 49152 B
    __shared__ float  wl[Cn];         //   768 B

    const int b  = blockIdx.y;
    const int u0 = blockIdx.x * UT;
    const int t  = threadIdx.x;

    const float* xb = x + (size_t)b * Nn * Cn;

    if (t < Cn) wl[t] = w[b * Cn + t];
    __syncthreads();

    // stage su = x[b, KEPT+u0+r, :] * w[b,:]   (linear layout, no swizzle)
    #pragma unroll
    for (int i = 0; i < UT * C4 / 512; ++i) {   // 12 iters
        int idx = t + 512 * i;
        int r = idx / C4, c4 = idx % C4;
        const float* src = xb + (size_t)(KEPT + u0 + r) * Cn + c4 * 4;
        float4 v;
        v.x = src[0] * wl[c4 * 4 + 0];
        v.y = src[1] * wl[c4 * 4 + 1];
        v.z = src[2] * wl[c4 * 4 + 2];
        v.w = src[3] * wl[c4 * 4 + 3];
        su[r * C4 + c4] = v;
    }

    // prefetch sk tile 0 into registers (T14 async-stage split)
    float4 pf[6];
    #pragma unroll
    for (int i = 0; i < 6; ++i) {
        int idx = t + 512 * i;
        int r = idx / C4, c4 = idx % C4;
        pf[i] = *reinterpret_cast<const float4*>(xb + (size_t)r * Cn + c4 * 4);
    }

    const int tk = t & 15;          // k group: 4 k's
    const int ch = (t >> 4) & 1;    // c4 half
    const int ti = t >> 5;          // u group: 8 u's
    const int kb = tk & 7;          // sk swizzle key for this thread's rows

    float best_v[8];
    int   best_i[8];
    #pragma unroll
    for (int i = 0; i < 8; ++i) { best_v[i] = -INFINITY; best_i[i] = 0; }

    for (int kt = 0; kt < KEPT / KT; ++kt) {
        __syncthreads();   // prior sk reads done (and su/wl stores at kt=0)
        #pragma unroll
        for (int i = 0; i < 6; ++i) {   // write prefetched tile to LDS (swizzled)
            int idx = t + 512 * i;
            int r = idx / C4, c4 = idx % C4;
            sk[r * C4 + (c4 ^ ((r >> 2) & 7))] = pf[i];
        }
        __syncthreads();
        if (kt < KEPT / KT - 1) {       // issue next tile's loads; hide under compute
            #pragma unroll
            for (int i = 0; i < 6; ++i) {
                int idx = t + 512 * i;
                int r = idx / C4, c4 = idx % C4;
                pf[i] = *reinterpret_cast<const float4*>(
                    xb + (size_t)((kt + 1) * KT + r) * Cn + c4 * 4);
            }
        }

        float acc[8][4];
        #pragma unroll
        for (int i = 0; i < 8; ++i)
            #pragma unroll
            for (int j = 0; j < 4; ++j) acc[i][j] = 0.f;

        for (int s = 0; s < 3; ++s) {          // 3 x 8 = 24 c4's per thread
            #pragma unroll
            for (int q = 0; q < 8; ++q) {
                int c4 = ch * 24 + s * 8 + q;
                float4 a[8];
                #pragma unroll
                for (int i = 0; i < 8; ++i)
                    a[i] = su[(ti * 8 + i) * C4 + c4];      // broadcast, linear
                float4 bb[4];
                #pragma unroll
                for (int j = 0; j < 4; ++j)
                    bb[j] = sk[(tk * 4 + j) * C4 + (c4 ^ kb)];
                #pragma unroll
                for (int i = 0; i < 8; ++i)
                    #pragma unroll
                    for (int j = 0; j < 4; ++j) {
                        acc[i][j] += a[i].x * bb[j].x;
                        acc[i][j] += a[i].y * bb[j].y;
                        acc[i][j] += a[i].z * bb[j].z;
                        acc[i][j] += a[i].w * bb[j].w;
                    }
            }
        }

        // combine the two c4-halves (lanes t and t^16), then running argmax
        #pragma unroll
        for (int i = 0; i < 8; ++i)
            #pragma unroll
            for (int j = 0; j < 4; ++j) {
                acc[i][j] += __shfl_xor(acc[i][j], 16);
                int k = kt * KT + tk * 4 + j;
                if (k != 0 && acc[i][j] > best_v[i]) {
                    best_v[i] = acc[i][j]; best_i[i] = k;
                }
            }
    }

    // argmax-reduce across tk (offsets 1..8; ch halves hold identical values)
    #pragma unroll
    for (int i = 0; i < 8; ++i) {
        #pragma unroll
        for (int off = 1; off < 16; off <<= 1) {
            float vv = __shfl_xor(best_v[i], off);
            int   ii = __shfl_xor(best_i[i], off);
            if (vv > best_v[i] || (vv == best_v[i] && ii < best_i[i])) {
                best_v[i] = vv; best_i[i] = ii;
            }
        }
    }
    if ((t & 31) == 0) {
        #pragma unroll
        for (int i = 0; i < 8; ++i)
            dst_idx[b * COMP + u0 + ti * 8 + i] = best_i[i];
    }
}

// ------------- Kernel C: scatter-add + mean -> out -------------
__global__ __launch_bounds__(256) void merge_kernel(const float* __restrict__ x,
                                                    const int* __restrict__ dst_idx,
                                                    float* __restrict__ out) {
    __shared__ float sums[KEPT][64];   // 65536 B
    __shared__ float cnt[KEPT];
    __shared__ int   sidx[COMP];

    int b = blockIdx.x;
    int cbase = blockIdx.y * 64;
    int t = threadIdx.x;

    for (int i = t; i < KEPT * 64; i += 256) ((float*)sums)[i] = 0.f;
    if (t < KEPT) cnt[t] = 0.f;
    sidx[t]       = dst_idx[b * COMP + t];
    sidx[t + 256] = dst_idx[b * COMP + t + 256];
    __syncthreads();

    atomicAdd(&cnt[sidx[t]], 1.0f);
    atomicAdd(&cnt[sidx[t + 256]], 1.0f);

    const float* xb = x + (size_t)b * Nn * Cn;
    int c  = t & 63;
    int ug = t >> 6;                       // 0..3
    for (int step = 0; step < COMP / 4; ++step) {
        int u = step * 4 + ug;
        float v = xb[(size_t)(KEPT + u) * Cn + cbase + c];
        atomicAdd(&sums[sidx[u]][c], v);
    }
    __syncthreads();

    float* outb = out + (size_t)b * KEPT * Cn;
    for (int i = t; i < KEPT * 64; i += 256) {
        int k = i >> 6, cc = i & 63;
        float d = xb[(size_t)k * Cn + cbase + cc];
        outb[(size_t)k * Cn + cbase + cc] = (d + sums[k][cc]) / (cnt[k] + 1.0f);
    }
}

extern "C" void kernel_launch(void* const* d_in, const int* in_sizes, int n_in,
                              void* d_out, int out_size, void* d_ws, size_t ws_size,
                              hipStream_t stream) {
    const float* x = (const float*)d_in[0];
    float* out = (float*)d_out;

    float* w       = (float*)d_ws;                                // 512*192 f32
    int*   dst_idx = (int*)((char*)d_ws + (size_t)512 * Cn * 4);  // 512*512 i32

    norm_kernel<<<dim3(512), dim3(768), 0, stream>>>(x, w);
    sim_argmax_kernel<<<dim3(COMP / UT, 512), dim3(512), 0, stream>>>(x, w, dst_idx);
    merge_kernel<<<dim3(512, 3), dim3(256), 0, stream>>>(x, dst_idx, out);
}